// Round 4
// baseline (115.959 us; speedup 1.0000x reference)
//
#include <hip/hip_runtime.h>
#include <hip/hip_bf16.h>

#define EPS 1e-7f
#define LOG2E 1.4426950408889634f

typedef float f32x4 __attribute__((ext_vector_type(4)));

// sigmoid(s*ln(r) + b) = 1 / (1 + exp(-(s*ln r + b)))
//                      = 1 / (1 + 2^(ns*log2(r) + nwb)),  ns = -s, nwb = -b*log2e
__device__ __forceinline__ float pers_elem(float p, float ns, float nwb) {
    p = fminf(fmaxf(p, EPS), 1.0f - EPS);
    float r = p * __builtin_amdgcn_rcpf(1.0f - p);   // p/(1-p), 1-ulp rcp
    float t = __log2f(r);                            // v_log_f32
    float e = exp2f(fmaf(ns, t, nwb));               // v_exp_f32
    return __builtin_amdgcn_rcpf(1.0f + e);          // sigmoid
}

// One block per batch row b. Row = S*H floats (3200) = 800 float4.
// Thread stride in floats (1024) is a multiple of H=16, so each thread's
// h-phase is loop-invariant -> hoist scale/bias (negated / pre-scaled by
// log2e) out of the loop. Streaming data (probs/out) has zero reuse ->
// nontemporal loads/stores keep L2 free for the gathered table rows.
__global__ __launch_bounds__(256) void PersonalizationLayer_30528627540712_kernel(
    const float* __restrict__ probs,
    const float* __restrict__ scale_table,
    const float* __restrict__ bias_table,
    const int*   __restrict__ user_idx,
    float*       __restrict__ out,
    int row4)   // row length in float4 units (S*H/4)
{
    const int b   = blockIdx.x;
    const int tid = threadIdx.x;
    const int u   = user_idx[b];

    // h-phase for this thread's float4s: (tid*4) % 16
    const int h0 = (tid & 3) * 4;
    const f32x4 s4 = *reinterpret_cast<const f32x4*>(&scale_table[(size_t)u * 16 + h0]);
    const f32x4 w4 = *reinterpret_cast<const f32x4*>(&bias_table [(size_t)u * 16 + h0]);

    const f32x4 ns4  = -s4;
    const f32x4 nwb4 = w4 * (-LOG2E);

    const f32x4* __restrict__ in = reinterpret_cast<const f32x4*>(probs) + (size_t)b * row4;
    f32x4*       __restrict__ o  = reinterpret_cast<f32x4*>(out) + (size_t)b * row4;

    for (int j = tid; j < row4; j += 256) {
        f32x4 p = __builtin_nontemporal_load(in + j);
        f32x4 r;
        r.x = pers_elem(p.x, ns4.x, nwb4.x);
        r.y = pers_elem(p.y, ns4.y, nwb4.y);
        r.z = pers_elem(p.z, ns4.z, nwb4.z);
        r.w = pers_elem(p.w, ns4.w, nwb4.w);
        __builtin_nontemporal_store(r, o + j);
    }
}

extern "C" void kernel_launch(void* const* d_in, const int* in_sizes, int n_in,
                              void* d_out, int out_size, void* d_ws, size_t ws_size,
                              hipStream_t stream) {
    const float* probs       = (const float*)d_in[0];
    const float* scale_table = (const float*)d_in[1];
    const float* bias_table  = (const float*)d_in[2];
    const int*   user_idx    = (const int*)d_in[3];
    float* out = (float*)d_out;

    const int B    = in_sizes[3];            // 4096
    const int row  = in_sizes[0] / B;        // S*H = 3200
    const int row4 = row / 4;                // 800

    PersonalizationLayer_30528627540712_kernel<<<B, 256, 0, stream>>>(
        probs, scale_table, bias_table, user_idx, out, row4);
}

// Round 5
// 109.725 us; speedup vs baseline: 1.0568x; 1.0568x over previous
//
#include <hip/hip_runtime.h>
#include <hip/hip_bf16.h>

#define EPS 1e-7f
#define LOG2E 1.4426950408889634f

typedef float f32x4 __attribute__((ext_vector_type(4)));

// sigmoid(s*ln(r) + b) = 1 / (1 + exp(-(s*ln r + b)))
//                      = 1 / (1 + 2^(ns*log2(r) + nwb)),  ns = -s, nwb = -b*log2e
__device__ __forceinline__ float pers_elem(float p, float ns, float nwb) {
    p = fminf(fmaxf(p, EPS), 1.0f - EPS);
    float r = p * __builtin_amdgcn_rcpf(1.0f - p);   // p/(1-p), 1-ulp rcp
    float t = __log2f(r);                            // v_log_f32
    float e = exp2f(fmaf(ns, t, nwb));               // v_exp_f32
    return __builtin_amdgcn_rcpf(1.0f + e);          // sigmoid
}

// One block per batch row b. Row = S*H floats (3200) = 800 float4.
// Thread stride in floats (1024) is a multiple of H=16, so each thread's
// h-phase is loop-invariant -> hoist scale/bias (negated / pre-scaled by
// log2e) out of the loop. A/B vs round 4: nontemporal hints REMOVED
// (round-4 nt build was +4.6us vs round-2; isolating whether nt stores
// pay a fabric penalty on the 52 MB output drain).
__global__ __launch_bounds__(256) void PersonalizationLayer_30528627540712_kernel(
    const float* __restrict__ probs,
    const float* __restrict__ scale_table,
    const float* __restrict__ bias_table,
    const int*   __restrict__ user_idx,
    float*       __restrict__ out,
    int row4)   // row length in float4 units (S*H/4)
{
    const int b   = blockIdx.x;
    const int tid = threadIdx.x;
    const int u   = user_idx[b];

    // h-phase for this thread's float4s: (tid*4) % 16
    const int h0 = (tid & 3) * 4;
    const f32x4 s4 = *reinterpret_cast<const f32x4*>(&scale_table[(size_t)u * 16 + h0]);
    const f32x4 w4 = *reinterpret_cast<const f32x4*>(&bias_table [(size_t)u * 16 + h0]);

    const f32x4 ns4  = -s4;
    const f32x4 nwb4 = w4 * (-LOG2E);

    const f32x4* __restrict__ in = reinterpret_cast<const f32x4*>(probs) + (size_t)b * row4;
    f32x4*       __restrict__ o  = reinterpret_cast<f32x4*>(out) + (size_t)b * row4;

    for (int j = tid; j < row4; j += 256) {
        f32x4 p = in[j];
        f32x4 r;
        r.x = pers_elem(p.x, ns4.x, nwb4.x);
        r.y = pers_elem(p.y, ns4.y, nwb4.y);
        r.z = pers_elem(p.z, ns4.z, nwb4.z);
        r.w = pers_elem(p.w, ns4.w, nwb4.w);
        o[j] = r;
    }
}

extern "C" void kernel_launch(void* const* d_in, const int* in_sizes, int n_in,
                              void* d_out, int out_size, void* d_ws, size_t ws_size,
                              hipStream_t stream) {
    const float* probs       = (const float*)d_in[0];
    const float* scale_table = (const float*)d_in[1];
    const float* bias_table  = (const float*)d_in[2];
    const int*   user_idx    = (const int*)d_in[3];
    float* out = (float*)d_out;

    const int B    = in_sizes[3];            // 4096
    const int row  = in_sizes[0] / B;        // S*H = 3200
    const int row4 = row / 4;                // 800

    PersonalizationLayer_30528627540712_kernel<<<B, 256, 0, stream>>>(
        probs, scale_table, bias_table, user_idx, out, row4);
}